// Round 1
// baseline (216.563 us; speedup 1.0000x reference)
//
#include <hip/hip_runtime.h>

#define BS     2
#define C_IN   64
#define NP     1024
#define NA     60
#define NA_OUT 60
#define KS     3
#define ANN    8
#define C_OUT  128
#define KDIM   (C_IN*KS)   // 192

// One block per (b,p). 256 threads.
// LDS: smem0 = 4096 floats (phase1: feats slice 64x60 = 3840; phase3: W k-tile 32x128 = 4096)
//      As    = 192*60 floats (gathered-weighted activations, [i=c*3+k][o])
__global__ __launch_bounds__(256, 2)
void intrazp_fused(const float* __restrict__ feats,
                   const float* __restrict__ intra_w,
                   const float* __restrict__ Wg,
                   const float* __restrict__ bias,
                   const int*   __restrict__ intra_idx,
                   float* __restrict__ out) {
    __shared__ float smem0[4096];          // fs[c*60+a]  /  Ws tile [kk*128+co]
    __shared__ float As[KDIM * NA_OUT];    // [i*60+o]

    const int t  = threadIdx.x;
    const int bp = blockIdx.x;
    const int b  = bp >> 10;
    const int p  = bp & 1023;

    // ---- phase 1: stage feats[b, :, p, :] into LDS ----
    {
        const float* fbase = feats + (size_t)b * C_IN * NP * NA + (size_t)p * NA;
        for (int j = t; j < C_IN * NA; j += 256) {
            int c = j / NA, a = j - c * NA;
            smem0[c * NA + a] = fbase[(size_t)c * NP * NA + a];
        }
    }
    __syncthreads();

    // ---- phase 2: As[(c*3+k)*60 + o] = sum_a fs[c, idx[o,k,a]] * w[o,k,a] ----
    if (t < NA_OUT * KS) {
        const int o = t / KS, k = t - o * KS;
        const int*   ip = intra_idx + (o * KS + k) * ANN;
        const float* wp = intra_w   + (o * KS + k) * ANN;
        int   idx[ANN];
        float w[ANN];
        #pragma unroll
        for (int a = 0; a < ANN; a++) { idx[a] = ip[a]; w[a] = wp[a]; }
        for (int c = 0; c < C_IN; c++) {
            const float* fr = smem0 + c * NA;
            float s = 0.f;
            #pragma unroll
            for (int a = 0; a < ANN; a++) s += fr[idx[a]] * w[a];
            As[(c * KS + k) * NA_OUT + o] = s;
        }
    }

    // ---- phase 3: out[co][o] = sum_i W[co][i] * As[i][o] ----
    // 240 active threads: g_co in 0..15 (8 co each), g_o in 0..14 (4 o each)
    const int g_co = t / 15;
    const int g_o  = t - g_co * 15;
    float acc[8][4];
    #pragma unroll
    for (int r = 0; r < 8; r++)
        #pragma unroll
        for (int s = 0; s < 4; s++) acc[r][s] = 0.f;

    for (int kt = 0; kt < KDIM / 32; kt++) {
        __syncthreads();   // smem0 free (phase2 reads done / previous tile consumed)
        // stage W[:, kt*32 .. kt*32+31] transposed into smem0[kk*128 + co]
        #pragma unroll
        for (int r4 = 0; r4 < 4; r4++) {
            int idx4 = t + r4 * 256;       // 0..1023
            int row  = idx4 >> 3;          // co 0..127
            int q    = idx4 & 7;           // float4 chunk within 32 k's
            float4 v = *(const float4*)(Wg + (size_t)row * KDIM + kt * 32 + q * 4);
            smem0[(q * 4 + 0) * 128 + row] = v.x;
            smem0[(q * 4 + 1) * 128 + row] = v.y;
            smem0[(q * 4 + 2) * 128 + row] = v.z;
            smem0[(q * 4 + 3) * 128 + row] = v.w;
        }
        __syncthreads();
        if (t < 240) {
            #pragma unroll 4
            for (int kk = 0; kk < 32; kk++) {
                int k = kt * 32 + kk;
                float4 a4 = *(const float4*)(As + k * NA_OUT + g_o * 4);
                float4 w0 = *(const float4*)(smem0 + kk * 128 + g_co * 8);
                float4 w1 = *(const float4*)(smem0 + kk * 128 + g_co * 8 + 4);
                const float av[4] = {a4.x, a4.y, a4.z, a4.w};
                const float wv[8] = {w0.x, w0.y, w0.z, w0.w, w1.x, w1.y, w1.z, w1.w};
                #pragma unroll
                for (int r = 0; r < 8; r++)
                    #pragma unroll
                    for (int s = 0; s < 4; s++)
                        acc[r][s] += wv[r] * av[s];
            }
        }
    }

    // ---- phase 4: add bias, write out[b, co, p, o] ----
    if (t < 240) {
        #pragma unroll
        for (int r = 0; r < 8; r++) {
            int co = g_co * 8 + r;
            float bv = bias[co];
            float4 v = make_float4(acc[r][0] + bv, acc[r][1] + bv,
                                   acc[r][2] + bv, acc[r][3] + bv);
            *(float4*)(out + (((size_t)b * C_OUT + co) * NP + p) * NA + g_o * 4) = v;
        }
    }
}

extern "C" void kernel_launch(void* const* d_in, const int* in_sizes, int n_in,
                              void* d_out, int out_size, void* d_ws, size_t ws_size,
                              hipStream_t stream) {
    const float* feats     = (const float*)d_in[0];
    const float* intra_w   = (const float*)d_in[1];
    const float* W         = (const float*)d_in[2];
    const float* bias      = (const float*)d_in[3];
    const int*   intra_idx = (const int*)d_in[4];
    float* out = (float*)d_out;

    intrazp_fused<<<dim3(BS * NP), dim3(256), 0, stream>>>(
        feats, intra_w, W, bias, intra_idx, out);
}

// Round 2
// 120.331 us; speedup vs baseline: 1.7997x; 1.7997x over previous
//
#include <hip/hip_runtime.h>

#define NPTS 1024
#define NA   60
#define CIN  64
#define KSZ  3
#define ANN  8
#define COUT 128
#define KD   192   // i' = k_s*64 + c, 6 k-tiles of 32

using bf16x8 = __attribute__((ext_vector_type(8))) short;
using f32x4  = __attribute__((ext_vector_type(4))) float;

__device__ __forceinline__ unsigned short f2bf(float f) {
    unsigned int u = __builtin_bit_cast(unsigned int, f);
    u += 0x7FFFu + ((u >> 16) & 1u);          // RNE
    return (unsigned short)(u >> 16);
}

// ---------------- pre-kernel: build W_frag + S_frag in d_ws ----------------
// ws[0 .. 24576)        : W_frag[mt=8][kt=6][lane=64][j=8]  bf16, A-frag layout,
//                         value = W[mt*16+(l&15)][ i=c*3+ks ] with i' = kt*32+8g+j = ks*64+c
// ws[24576 .. 36864)    : S_frag[nt=12][kt=2][lane=64][j=8] bf16, B-frag layout,
//                         value = S[a' = kt*32+8g+j][ n' = nt*16+(l&15) ],
//                         S[a'][ks*60+o] = sum_a w[o,ks,a]*[idx[o,ks,a]==a'], zero-padded
__global__ void build_tables(const float* __restrict__ intra_w,
                             const float* __restrict__ W,
                             const int*   __restrict__ intra_idx,
                             unsigned short* __restrict__ ws) {
    int f = blockIdx.x * 256 + threadIdx.x;
    if (f < 24576) {
        int j = f & 7, l = (f >> 3) & 63, x = f >> 9;
        int kt = x % 6, mt = x / 6;
        int m  = mt * 16 + (l & 15);
        int ip = kt * 32 + 8 * (l >> 4) + j;      // i'
        int c  = ip & 63, ks = ip >> 6;
        ws[f] = f2bf(W[m * KD + c * KSZ + ks]);
    } else if (f < 36864) {
        int f2 = f - 24576;
        int j = f2 & 7, l = (f2 >> 3) & 63;
        int kt = (f2 >> 9) & 1, nt = f2 >> 10;
        int np = nt * 16 + (l & 15);              // n' = ks*60+o
        int ap = kt * 32 + 8 * (l >> 4) + j;      // a'
        float s = 0.f;
        if (np < 180 && ap < 60) {
            int ks = (np >= 120) ? 2 : ((np >= 60) ? 1 : 0);
            int o  = np - 60 * ks;
            const int*   ix = intra_idx + (o * KSZ + ks) * ANN;
            const float* wx = intra_w   + (o * KSZ + ks) * ANN;
            #pragma unroll
            for (int a = 0; a < ANN; a++) s += (ix[a] == ap) ? wx[a] : 0.f;
        }
        ws[f] = f2bf(s);
    }
}

// ---------------- main kernel: one block per (b,p), 256 threads ----------------
__global__ __launch_bounds__(256, 3)
void intrazp_mfma(const float* __restrict__ feats,
                  const float* __restrict__ bias,
                  const unsigned short* __restrict__ ws,
                  float* __restrict__ out) {
    // As_T[o=64][i'=192] bf16, XOR-swizzled: byte(o,i') = (o*384 + i'*2) ^ ((o&7)<<4)
    __shared__ __align__(16) unsigned short AsT[64 * 192];

    const int t    = threadIdx.x;
    const int wave = t >> 6, lane = t & 63;
    const int l15  = lane & 15, g = lane >> 4;
    const int bp   = blockIdx.x;
    const int b    = bp >> 10, p = bp & 1023;

    // zero pad rows o = 60..63 (read as B2 cols 60..63, never stored)
    #pragma unroll
    for (int r = 0; r < 3; r++) AsT[60 * 192 + r * 256 + t] = 0;

    // ================= GEMM-1: G[c][(ks,o)] = fs(64x60) * S(60x180) =================
    // waves: wm = wave&1 -> mtiles {2wm,2wm+1}; wn = wave>>1 -> ntiles [6wn, 6wn+6)
    const unsigned short* Sfrag = ws + 24576;
    const int wm = wave & 1, wn = wave >> 1;

    // A1 fragments from global feats (f32 -> bf16)
    bf16x8 a1[2][2];
    {
        const float* fb = feats + ((size_t)b * CIN * NPTS + p) * NA;
        #pragma unroll
        for (int mi = 0; mi < 2; mi++) {
            int c = (2 * wm + mi) * 16 + l15;
            const float* fr = fb + (size_t)c * NPTS * NA;
            #pragma unroll
            for (int kt = 0; kt < 2; kt++) {
                int a0 = kt * 32 + 8 * g;                 // a' base (multiple of 4)
                float4 lo = *(const float4*)(fr + a0);
                int ah = a0 + 4;
                float4 hi = *(const float4*)(fr + ((ah < NA) ? ah : 0)); // dead lanes: stay in-bounds
                bf16x8 v;
                v[0] = (short)f2bf(lo.x); v[1] = (short)f2bf(lo.y);
                v[2] = (short)f2bf(lo.z); v[3] = (short)f2bf(lo.w);
                v[4] = (short)f2bf(hi.x); v[5] = (short)f2bf(hi.y);
                v[6] = (short)f2bf(hi.z); v[7] = (short)f2bf(hi.w);
                a1[mi][kt] = v;
            }
        }
    }

    #pragma unroll
    for (int ni = 0; ni < 6; ni++) {
        int nt = wn * 6 + ni;
        bf16x8 b0 = *(const bf16x8*)(Sfrag + ((nt * 2 + 0) * 64 + lane) * 8);
        bf16x8 b1 = *(const bf16x8*)(Sfrag + ((nt * 2 + 1) * 64 + lane) * 8);

        int np = nt * 16 + l15;                    // n' = ks*60 + o
        int ks = (np >= 120) ? 2 : ((np >= 60) ? 1 : 0);
        int o  = np - 60 * ks;
        int sw = (o & 7) << 4;
        int rowbyte = o * 384;

        #pragma unroll
        for (int mi = 0; mi < 2; mi++) {
            f32x4 acc = {0.f, 0.f, 0.f, 0.f};
            acc = __builtin_amdgcn_mfma_f32_16x16x32_bf16(a1[mi][0], b0, acc, 0, 0, 0);
            acc = __builtin_amdgcn_mfma_f32_16x16x32_bf16(a1[mi][1], b1, acc, 0, 0, 0);
            if (np < 180) {
                // rows c = mt*16 + 4g + r, r=0..3 -> i' = ks*64 + c consecutive
                int cbase = (2 * wm + mi) * 16 + 4 * g;
                int ipb   = ks * 64 + cbase;
                unsigned int lo = (unsigned int)f2bf(acc[0]) | ((unsigned int)f2bf(acc[1]) << 16);
                unsigned int hi = (unsigned int)f2bf(acc[2]) | ((unsigned int)f2bf(acc[3]) << 16);
                int byte = (rowbyte + ipb * 2) ^ sw;   // 8B-aligned (cbase mult of 4)
                *(uint2*)((char*)AsT + byte) = make_uint2(lo, hi);
            }
        }
    }

    __syncthreads();

    // ================= GEMM-2: out[co][o] = W(128x192) * As(192x60) + bias =================
    // waves: wm2 = wave&1 -> mtiles [4wm2, 4wm2+4); wn2 = wave>>1 -> ntiles {2wn2, 2wn2+1}
    const int wm2 = wave & 1, wn2 = wave >> 1;

    bf16x8 b2a[6], b2b[6];
    {
        int o0 = (2 * wn2 + 0) * 16 + l15;
        int o1 = (2 * wn2 + 1) * 16 + l15;
        int rb0 = o0 * 384, sw0 = (o0 & 7) << 4;
        int rb1 = o1 * 384, sw1 = (o1 & 7) << 4;
        #pragma unroll
        for (int kt = 0; kt < 6; kt++) {
            int x = (kt * 32 + 8 * g) * 2;         // 16B-aligned
            b2a[kt] = *(const bf16x8*)((char*)AsT + ((rb0 + x) ^ sw0));
            b2b[kt] = *(const bf16x8*)((char*)AsT + ((rb1 + x) ^ sw1));
        }
    }

    const int o0 = (2 * wn2 + 0) * 16 + l15;
    const int o1 = (2 * wn2 + 1) * 16 + l15;

    #pragma unroll
    for (int mj = 0; mj < 4; mj++) {
        int mt = wm2 * 4 + mj;
        f32x4 accA = {0.f, 0.f, 0.f, 0.f};
        f32x4 accB = {0.f, 0.f, 0.f, 0.f};
        #pragma unroll
        for (int kt = 0; kt < 6; kt++) {
            bf16x8 a2 = *(const bf16x8*)(ws + ((mt * 6 + kt) * 64 + lane) * 8);
            accA = __builtin_amdgcn_mfma_f32_16x16x32_bf16(a2, b2a[kt], accA, 0, 0, 0);
            accB = __builtin_amdgcn_mfma_f32_16x16x32_bf16(a2, b2b[kt], accB, 0, 0, 0);
        }
        int cbase = mt * 16 + 4 * g;
        float bv0 = bias[cbase + 0], bv1 = bias[cbase + 1];
        float bv2 = bias[cbase + 2], bv3 = bias[cbase + 3];
        float* ob = out + (((size_t)b * COUT + cbase) * NPTS + p) * NA;
        const size_t cs = (size_t)NPTS * NA;
        if (o0 < NA) {
            ob[0 * cs + o0] = accA[0] + bv0;
            ob[1 * cs + o0] = accA[1] + bv1;
            ob[2 * cs + o0] = accA[2] + bv2;
            ob[3 * cs + o0] = accA[3] + bv3;
        }
        if (o1 < NA) {
            ob[0 * cs + o1] = accB[0] + bv0;
            ob[1 * cs + o1] = accB[1] + bv1;
            ob[2 * cs + o1] = accB[2] + bv2;
            ob[3 * cs + o1] = accB[3] + bv3;
        }
    }
}

extern "C" void kernel_launch(void* const* d_in, const int* in_sizes, int n_in,
                              void* d_out, int out_size, void* d_ws, size_t ws_size,
                              hipStream_t stream) {
    const float* feats     = (const float*)d_in[0];
    const float* intra_w   = (const float*)d_in[1];
    const float* W         = (const float*)d_in[2];
    const float* bias      = (const float*)d_in[3];
    const int*   intra_idx = (const int*)d_in[4];
    float* out = (float*)d_out;
    unsigned short* ws = (unsigned short*)d_ws;   // needs 73728 B

    build_tables<<<dim3(144), dim3(256), 0, stream>>>(intra_w, W, intra_idx, ws);
    intrazp_mfma<<<dim3(2 * NPTS), dim3(256), 0, stream>>>(feats, bias, ws, out);
}